// Round 11
// baseline (1339.991 us; speedup 1.0000x reference)
//
#include <hip/hip_runtime.h>
#include <cstdint>
#include <cstddef>

// Problem constants (Swin window attention)
#define B_WIN   2048
#define N_TOK   64
#define C_DIM   512
#define H_HEADS 16
#define D_HEAD  32
#define K_DIM   512
#define M_ROWS  (B_WIN * 64)   // 131072

// Tiled operand layout for GEMM staging (bf16):
//   T[mb][kt][s][r][e]  mb=row>>7, kt=k>>5, s=(k>>3)&3, r=row&127, e=k&7
//   flat elem = mb*65536 + kt*4096 + s*1024 + r*8 + e

typedef __bf16 bf16x8 __attribute__((ext_vector_type(8)));
typedef float  f32x4  __attribute__((ext_vector_type(4)));
typedef unsigned short u16x8 __attribute__((ext_vector_type(8)));

__device__ __forceinline__ unsigned short f2bf_rn(float f) {
    unsigned u = __float_as_uint(f);
    u += 0x7fffu + ((u >> 16) & 1u);
    return (unsigned short)(u >> 16);
}
__device__ __forceinline__ float bf2f(unsigned short h) {
    return __uint_as_float(((unsigned)h) << 16);
}
__device__ __forceinline__ void gload16(const void* g, void* l) {
    __builtin_amdgcn_global_load_lds(
        (const __attribute__((address_space(1))) void*)g,
        (__attribute__((address_space(3))) void*)l,
        16, 0, 0);
}

// ---------------------------------------------------------------------------
// bias_expand: bias_hn[h][i][j] = table[rel[i][j]][h]   (65536 floats)
// ---------------------------------------------------------------------------
__global__ void bias_expand_kernel(const float* __restrict__ bias_table,
                                   const int* __restrict__ rel_index,
                                   float* __restrict__ bias_hn) {
    int tid = blockIdx.x * 256 + threadIdx.x;
    int h  = tid >> 12;
    int ij = tid & 4095;
    bias_hn[tid] = bias_table[rel_index[ij] * H_HEADS + h];
}

// ---------------------------------------------------------------------------
// xsplit: x [M][512] fp32 -> Xh/Xl bf16 hi/lo in TILED layout.
// ---------------------------------------------------------------------------
__global__ __launch_bounds__(256) void xsplit_kernel(
    const float* __restrict__ x,
    unsigned short* __restrict__ Xh,
    unsigned short* __restrict__ Xl)
{
    size_t e8 = ((size_t)blockIdx.x * 256 + threadIdx.x) * 8;
    const int mb = (int)(e8 >> 16);
    const int w  = (int)(e8 & 65535);
    const int kt = w >> 12;
    const int s  = (w >> 10) & 3;
    const int r  = (w >> 3) & 127;
    const int m  = mb * 128 + r;
    const int k  = kt * 32 + s * 8;
    const float* src = &x[(size_t)m * 512 + k];
    float4 f0 = *reinterpret_cast<const float4*>(src);
    float4 f1 = *reinterpret_cast<const float4*>(src + 4);
    float fv[8] = {f0.x, f0.y, f0.z, f0.w, f1.x, f1.y, f1.z, f1.w};
    u16x8 hi, lo;
#pragma unroll
    for (int j = 0; j < 8; ++j) {
        unsigned short h = f2bf_rn(fv[j]);
        hi[j] = h;
        lo[j] = f2bf_rn(fv[j] - bf2f(h));
    }
    *reinterpret_cast<u16x8*>(&Xh[e8]) = hi;
    *reinterpret_cast<u16x8*>(&Xl[e8]) = lo;
}

// ---------------------------------------------------------------------------
// wsplit: w[512 k][Ncols n] -> wTh/wTl (rows=n, 512 k) in TILED layout
// ---------------------------------------------------------------------------
__global__ __launch_bounds__(256) void wsplit_kernel(
    const float* __restrict__ w,
    unsigned short* __restrict__ wTh,
    unsigned short* __restrict__ wTl,
    int Ncols)
{
    size_t e8 = ((size_t)blockIdx.x * 256 + threadIdx.x) * 8;
    const int mb = (int)(e8 >> 16);
    const int ww = (int)(e8 & 65535);
    const int kt = ww >> 12;
    const int s  = (ww >> 10) & 3;
    const int r  = (ww >> 3) & 127;
    const int n  = mb * 128 + r;
    const int k  = kt * 32 + s * 8;
    u16x8 hi, lo;
#pragma unroll
    for (int j = 0; j < 8; ++j) {
        float v = w[(size_t)(k + j) * Ncols + n];
        unsigned short h = f2bf_rn(v);
        hi[j] = h;
        lo[j] = f2bf_rn(v - bf2f(h));
    }
    *reinterpret_cast<u16x8*>(&wTh[e8]) = hi;
    *reinterpret_cast<u16x8*>(&wTl[e8]) = lo;
}

// ---------------------------------------------------------------------------
// bf16x3-split MFMA GEMM, 128x128 tile, BK=32, 16 steps, 8 waves (512 thr),
// mfma_f32_16x16x32_bf16 (R7-proven dataflow) with a 4-BUFFER LDS RING:
// prologue stages tiles 0..2; each iter stages tile ks+3 and waits a COUNTED
// vmcnt(8) (oldest in-flight stage landed ~2 steps ago) -> the barrier no
// longer waits on HBM latency. 128 KiB LDS -> 1 block/CU (8 waves, 2/SIMD).
// ---------------------------------------------------------------------------
__global__ __launch_bounds__(512, 2) void gemm_mfma_kernel(
    const unsigned short* __restrict__ ATh,
    const unsigned short* __restrict__ ATl,
    const unsigned short* __restrict__ BTh,
    const unsigned short* __restrict__ BTl,
    int mode,
    float* __restrict__ qkv_out,
    const float* __restrict__ bias,
    float* __restrict__ out,
    int Ncols_out,
    int nb_grid)
{
    __shared__ __align__(16) unsigned short L[4][4][4096];  // 128 KiB ring

    const int t    = threadIdx.x;
    const int lane = t & 63;
    const int wave = t >> 6;             // 0..7
    const int lg   = lane >> 4;          // k-octet 0..3
    const int lr   = lane & 15;          // row within fragment
    const int wrow = (wave >> 1) * 32;   // 0,32,64,96
    const int wcol = (wave & 1) * 64;    // 0,64

    const int lin = blockIdx.x + gridDim.x * blockIdx.y;
    const int nwg = gridDim.x * gridDim.y;
    const int cpx = nwg >> 3;
    const int swz = (lin & 7) * cpx + (lin >> 3);
    const int m0  = (swz / nb_grid) * 128;
    const int n0  = (swz % nb_grid) * 128;
    const size_t tbA = (size_t)(m0 >> 7) * 16 * 4096;
    const size_t tbB = (size_t)(n0 >> 7) * 16 * 4096;

    f32x4 acc[2][4];
#pragma unroll
    for (int i = 0; i < 2; ++i)
#pragma unroll
        for (int j = 0; j < 4; ++j) acc[i][j] = (f32x4){0.f, 0.f, 0.f, 0.f};

    // stage all 4 operand tiles for K-step kt into ring slot bi (4 gloads)
    auto stage = [&](int kt, int bi) {
        const size_t bA = tbA + (size_t)kt * 4096 + (size_t)t * 8;
        const size_t bB = tbB + (size_t)kt * 4096 + (size_t)t * 8;
        gload16(&ATh[bA], &L[bi][0][t * 8]);
        gload16(&ATl[bA], &L[bi][1][t * 8]);
        gload16(&BTh[bB], &L[bi][2][t * 8]);
        gload16(&BTl[bB], &L[bi][3][t * 8]);
    };

    // prologue: 3 stages in flight; wait only for stage(0) (8 newest allowed)
    stage(0, 0);
    stage(1, 1);
    stage(2, 2);
    asm volatile("s_waitcnt vmcnt(8)" ::: "memory");
    __builtin_amdgcn_sched_barrier(0);
    __builtin_amdgcn_s_barrier();
    __builtin_amdgcn_sched_barrier(0);

#pragma unroll
    for (int ks = 0; ks < 16; ++ks) {
        const int cur = ks & 3;
        // ring slot (ks+3)&3 was consumed at iter ks-1 (barrier-ordered)
        if (ks + 3 < 16) stage(ks + 3, (ks + 3) & 3);

        bf16x8 ah[2], al[2];
#pragma unroll
        for (int mi = 0; mi < 2; ++mi) {
            const int off = lg * 1024 + (wrow + mi * 16 + lr) * 8;
            ah[mi] = *reinterpret_cast<const bf16x8*>(&L[cur][0][off]);
            al[mi] = *reinterpret_cast<const bf16x8*>(&L[cur][1][off]);
        }
        __builtin_amdgcn_s_setprio(1);
#pragma unroll
        for (int ni = 0; ni < 4; ++ni) {
            const int off = lg * 1024 + (wcol + ni * 16 + lr) * 8;
            bf16x8 bh = *reinterpret_cast<const bf16x8*>(&L[cur][2][off]);
            bf16x8 bl = *reinterpret_cast<const bf16x8*>(&L[cur][3][off]);
#pragma unroll
            for (int mi = 0; mi < 2; ++mi) {
                acc[mi][ni] = __builtin_amdgcn_mfma_f32_16x16x32_bf16(ah[mi], bh, acc[mi][ni], 0, 0, 0);
                acc[mi][ni] = __builtin_amdgcn_mfma_f32_16x16x32_bf16(ah[mi], bl, acc[mi][ni], 0, 0, 0);
                acc[mi][ni] = __builtin_amdgcn_mfma_f32_16x16x32_bf16(al[mi], bh, acc[mi][ni], 0, 0, 0);
            }
        }
        __builtin_amdgcn_s_setprio(0);

        // counted drain: require stage(ks+1) landed; keep 2 newer stages
        // (8 loads) in flight across the barrier. In-flight at this point:
        // ks<=12: {ks+1,ks+2,ks+3}->vmcnt(8); ks==13: {14,15}->vmcnt(4);
        // ks==14: {15}->vmcnt(0); ks==15: none.
        if (ks < 13) {
            asm volatile("s_waitcnt vmcnt(8)" ::: "memory");
        } else if (ks == 13) {
            asm volatile("s_waitcnt vmcnt(4)" ::: "memory");
        } else if (ks == 14) {
            asm volatile("s_waitcnt vmcnt(0)" ::: "memory");
        }
        if (ks < 15) {
            __builtin_amdgcn_sched_barrier(0);
            __builtin_amdgcn_s_barrier();
            __builtin_amdgcn_sched_barrier(0);
        }
    }

    // C/D layout: col = lane&15, row = (lane>>4)*4 + reg   [m89-verified]
    if (mode == 0) {
#pragma unroll
        for (int mi = 0; mi < 2; ++mi)
#pragma unroll
            for (int ni = 0; ni < 4; ++ni) {
                const int col  = n0 + wcol + ni * 16 + lr;
                const int tsel = col >> 9;
                const int h    = (col >> 5) & 15;
                const int dd   = col & 31;
#pragma unroll
                for (int reg = 0; reg < 4; ++reg) {
                    const int row = m0 + wrow + mi * 16 + lg * 4 + reg;
                    const int b = row >> 6, n = row & 63;
                    qkv_out[((((size_t)tsel * B_WIN + b) * H_HEADS + h) * N_TOK + n) * D_HEAD + dd]
                        = acc[mi][ni][reg];
                }
            }
    } else {
#pragma unroll
        for (int mi = 0; mi < 2; ++mi)
#pragma unroll
            for (int ni = 0; ni < 4; ++ni) {
                const int col = n0 + wcol + ni * 16 + lr;
                const float pb = bias[col];
#pragma unroll
                for (int reg = 0; reg < 4; ++reg) {
                    const int row = m0 + wrow + mi * 16 + lg * 4 + reg;
                    out[(size_t)row * Ncols_out + col] = acc[mi][ni][reg] + pb;
                }
            }
    }
}

// ---------------------------------------------------------------------------
// MFMA window attention (unchanged from R6/R7 — proven)
// ---------------------------------------------------------------------------
__global__ __launch_bounds__(256, 4) void attn_kernel(
    const float* __restrict__ qkv,        // [3][B][H][N][D]
    const float* __restrict__ bias_hn,    // [H][64][64]
    float* __restrict__ attn_map,         // [B][H][64][64]
    unsigned short* __restrict__ avh,     // tiled bf16 hi
    unsigned short* __restrict__ avl)     // tiled bf16 lo
{
    __shared__ __align__(16) unsigned short SM[14848];
    constexpr int QH = 0, QL = 2560, KH = 5120, KL = 7680;   // [64][40]
    constexpr int PH = 0, PL = 4608;                         // [64][72]
    constexpr int VTH = 10240, VTL = 12544;                  // [32][72]

    const int bh   = blockIdx.x;
    const int b    = bh >> 4;
    const int h    = bh & 15;
    const int t    = threadIdx.x;
    const int lane = t & 63;
    const int wv   = t >> 6;
    const int lg   = lane >> 4;
    const int lr   = lane & 15;

    const size_t plane = (size_t)B_WIN * H_HEADS * N_TOK * D_HEAD;
    const size_t base  = (size_t)bh * (N_TOK * D_HEAD);
    const float* qg = qkv + base;
    const float* kg = qkv + plane + base;
    const float* vg = qkv + 2 * plane + base;

    {
        const int r  = t >> 2;
        const int c0 = (t & 3) * 8;
        float4 a0 = *reinterpret_cast<const float4*>(&qg[r * 32 + c0]);
        float4 a1 = *reinterpret_cast<const float4*>(&qg[r * 32 + c0 + 4]);
        float qv[8] = {a0.x, a0.y, a0.z, a0.w, a1.x, a1.y, a1.z, a1.w};
        u16x8 hi, lo;
#pragma unroll
        for (int j = 0; j < 8; ++j) {
            unsigned short hh = f2bf_rn(qv[j]);
            hi[j] = hh; lo[j] = f2bf_rn(qv[j] - bf2f(hh));
        }
        *reinterpret_cast<u16x8*>(&SM[QH + r * 40 + c0]) = hi;
        *reinterpret_cast<u16x8*>(&SM[QL + r * 40 + c0]) = lo;

        float4 k0 = *reinterpret_cast<const float4*>(&kg[r * 32 + c0]);
        float4 k1 = *reinterpret_cast<const float4*>(&kg[r * 32 + c0 + 4]);
        float kv[8] = {k0.x, k0.y, k0.z, k0.w, k1.x, k1.y, k1.z, k1.w};
#pragma unroll
        for (int j = 0; j < 8; ++j) {
            unsigned short hh = f2bf_rn(kv[j]);
            hi[j] = hh; lo[j] = f2bf_rn(kv[j] - bf2f(hh));
        }
        *reinterpret_cast<u16x8*>(&SM[KH + r * 40 + c0]) = hi;
        *reinterpret_cast<u16x8*>(&SM[KL + r * 40 + c0]) = lo;

        float4 v0 = *reinterpret_cast<const float4*>(&vg[r * 32 + c0]);
        float4 v1 = *reinterpret_cast<const float4*>(&vg[r * 32 + c0 + 4]);
        float vv[8] = {v0.x, v0.y, v0.z, v0.w, v1.x, v1.y, v1.z, v1.w};
#pragma unroll
        for (int u = 0; u < 8; ++u) {
            const int d = c0 + u;
            unsigned short hh = f2bf_rn(vv[u]);
            SM[VTH + d * 72 + r] = hh;
            SM[VTL + d * 72 + r] = f2bf_rn(vv[u] - bf2f(hh));
        }
    }
    __syncthreads();

    float bias[4][4];
#pragma unroll
    for (int reg = 0; reg < 4; ++reg)
#pragma unroll
        for (int c = 0; c < 4; ++c)
            bias[reg][c] = bias_hn[(h << 12) + ((wv * 16 + lg * 4 + reg) << 6) + c * 16 + lr];

    const int ar = wv * 16 + lr;
    bf16x8 qa_h = *reinterpret_cast<const bf16x8*>(&SM[QH + ar * 40 + lg * 8]);
    bf16x8 qa_l = *reinterpret_cast<const bf16x8*>(&SM[QL + ar * 40 + lg * 8]);
    f32x4 S[4];
#pragma unroll
    for (int c = 0; c < 4; ++c) {
        const int br = c * 16 + lr;
        bf16x8 kb_h = *reinterpret_cast<const bf16x8*>(&SM[KH + br * 40 + lg * 8]);
        bf16x8 kb_l = *reinterpret_cast<const bf16x8*>(&SM[KL + br * 40 + lg * 8]);
        f32x4 s = (f32x4){0.f, 0.f, 0.f, 0.f};
        s = __builtin_amdgcn_mfma_f32_16x16x32_bf16(qa_h, kb_h, s, 0, 0, 0);
        s = __builtin_amdgcn_mfma_f32_16x16x32_bf16(qa_h, kb_l, s, 0, 0, 0);
        s = __builtin_amdgcn_mfma_f32_16x16x32_bf16(qa_l, kb_h, s, 0, 0, 0);
        S[c] = s;
    }
    __syncthreads();   // Q/K region dead -> reusable for P

    const float scale = 0.1767766952966369f;  // 32^-0.5
    float p[4][4], mx[4], sm[4];
#pragma unroll
    for (int reg = 0; reg < 4; ++reg) mx[reg] = -1e30f;
#pragma unroll
    for (int reg = 0; reg < 4; ++reg)
#pragma unroll
        for (int c = 0; c < 4; ++c) {
            float s = fmaf(S[c][reg], scale, bias[reg][c]);
            p[reg][c] = s;
            mx[reg] = fmaxf(mx[reg], s);
        }
#pragma unroll
    for (int reg = 0; reg < 4; ++reg) {
        mx[reg] = fmaxf(mx[reg], __shfl_xor(mx[reg], 1));
        mx[reg] = fmaxf(mx[reg], __shfl_xor(mx[reg], 2));
        mx[reg] = fmaxf(mx[reg], __shfl_xor(mx[reg], 4));
        mx[reg] = fmaxf(mx[reg], __shfl_xor(mx[reg], 8));
        sm[reg] = 0.f;
    }
#pragma unroll
    for (int reg = 0; reg < 4; ++reg)
#pragma unroll
        for (int c = 0; c < 4; ++c) {
            float e = __expf(p[reg][c] - mx[reg]);
            p[reg][c] = e;
            sm[reg] += e;
        }
#pragma unroll
    for (int reg = 0; reg < 4; ++reg) {
        sm[reg] += __shfl_xor(sm[reg], 1);
        sm[reg] += __shfl_xor(sm[reg], 2);
        sm[reg] += __shfl_xor(sm[reg], 4);
        sm[reg] += __shfl_xor(sm[reg], 8);
        const float inv = 1.0f / sm[reg];
#pragma unroll
        for (int c = 0; c < 4; ++c) p[reg][c] *= inv;
    }

    const size_t amb = (size_t)bh * 4096;
#pragma unroll
    for (int reg = 0; reg < 4; ++reg) {
        const int R = wv * 16 + lg * 4 + reg;
#pragma unroll
        for (int c = 0; c < 4; ++c) {
            const int C = c * 16 + lr;
            const float own = p[reg][c];
            attn_map[amb + R * 64 + C] = own;
            const float mate = __shfl_xor(own, 1);
            if (!(lr & 1)) {
                unsigned short h0 = f2bf_rn(own);
                unsigned short l0 = f2bf_rn(own - bf2f(h0));
                unsigned short h1 = f2bf_rn(mate);
                unsigned short l1 = f2bf_rn(mate - bf2f(h1));
                *reinterpret_cast<unsigned*>(&SM[PH + R * 72 + C]) =
                    (unsigned)h0 | ((unsigned)h1 << 16);
                *reinterpret_cast<unsigned*>(&SM[PL + R * 72 + C]) =
                    (unsigned)l0 | ((unsigned)l1 << 16);
            }
        }
    }
    // no barrier: wave w's PV a-frags read rows 16wv..16wv+15 = its own writes

    f32x4 O[2];
    O[0] = (f32x4){0.f, 0.f, 0.f, 0.f};
    O[1] = (f32x4){0.f, 0.f, 0.f, 0.f};
#pragma unroll
    for (int kk = 0; kk < 2; ++kk) {
        const int pr = wv * 16 + lr;
        bf16x8 pa_h = *reinterpret_cast<const bf16x8*>(&SM[PH + pr * 72 + kk * 32 + lg * 8]);
        bf16x8 pa_l = *reinterpret_cast<const bf16x8*>(&SM[PL + pr * 72 + kk * 32 + lg * 8]);
#pragma unroll
        for (int n = 0; n < 2; ++n) {
            const int vr = n * 16 + lr;
            bf16x8 vb_h = *reinterpret_cast<const bf16x8*>(&SM[VTH + vr * 72 + kk * 32 + lg * 8]);
            bf16x8 vb_l = *reinterpret_cast<const bf16x8*>(&SM[VTL + vr * 72 + kk * 32 + lg * 8]);
            O[n] = __builtin_amdgcn_mfma_f32_16x16x32_bf16(pa_h, vb_h, O[n], 0, 0, 0);
            O[n] = __builtin_amdgcn_mfma_f32_16x16x32_bf16(pa_h, vb_l, O[n], 0, 0, 0);
            O[n] = __builtin_amdgcn_mfma_f32_16x16x32_bf16(pa_l, vb_h, O[n], 0, 0, 0);
        }
    }

    const int mb = b >> 1;
#pragma unroll
    for (int n = 0; n < 2; ++n)
#pragma unroll
        for (int reg = 0; reg < 4; ++reg) {
            const int R  = wv * 16 + lg * 4 + reg;
            const int d  = n * 16 + lr;
            const int rl = (b & 1) * 64 + R;
            const float o = O[n][reg];
            unsigned short oh = f2bf_rn(o);
            unsigned short ol = f2bf_rn(o - bf2f(oh));
            size_t off = (size_t)mb * 65536 + (size_t)h * 4096
                       + (size_t)(d >> 3) * 1024 + (size_t)rl * 8 + (d & 7);
            avh[off] = oh;
            avl[off] = ol;
        }
}

// ---------------------------------------------------------------------------
extern "C" void kernel_launch(void* const* d_in, const int* in_sizes, int n_in,
                              void* d_out, int out_size, void* d_ws, size_t ws_size,
                              hipStream_t stream) {
    const float* x          = (const float*)d_in[0];
    const float* qkv_w      = (const float*)d_in[1];
    const float* proj_w     = (const float*)d_in[2];
    const float* proj_b     = (const float*)d_in[3];
    const float* bias_table = (const float*)d_in[4];
    const int*   rel_index  = (const int*)d_in[5];

    float* out      = (float*)d_out;                           // [131072][512]
    float* attn_map = (float*)d_out + (size_t)M_ROWS * C_DIM;  // [B][H][64][64]

    // d_ws: Xh | Xl (tiled bf16) | qkv fp32   (same as R7)
    // avh/avl alias Xh/Xl (dead after QKV GEMM).
    unsigned short* Xh  = (unsigned short*)d_ws;
    unsigned short* Xl  = Xh + (size_t)M_ROWS * 512;
    float*          qkv = (float*)(Xl + (size_t)M_ROWS * 512);
    unsigned short* avh = Xh;
    unsigned short* avl = Xl;

    // parking: qkv_w split -> attn_map region of d_out (dead until attn
    // overwrites it); proj_w split -> qkv head (dead after attn reads qkv);
    // bias_hn -> out head (out written only by the final proj GEMM).
    unsigned short* qwTh = (unsigned short*)attn_map;
    unsigned short* qwTl = qwTh + (size_t)1536 * 512;
    unsigned short* pwTh = (unsigned short*)qkv;
    unsigned short* pwTl = pwTh + (size_t)512 * 512;
    float* bias_hn = out;   // 65536 floats at head of out region

    bias_expand_kernel<<<256, 256, 0, stream>>>(bias_table, rel_index, bias_hn);
    xsplit_kernel<<<M_ROWS * 512 / 2048, 256, 0, stream>>>(x, Xh, Xl);
    wsplit_kernel<<<384, 256, 0, stream>>>(qkv_w, qwTh, qwTl, 1536);
    gemm_mfma_kernel<<<dim3(12, 1024), 512, 0, stream>>>(
        Xh, Xl, qwTh, qwTl, 0, qkv, nullptr, nullptr, 1536, 12);
    attn_kernel<<<B_WIN * H_HEADS, 256, 0, stream>>>(
        qkv, bias_hn, attn_map, avh, avl);
    wsplit_kernel<<<128, 256, 0, stream>>>(proj_w, pwTh, pwTl, 512);
    gemm_mfma_kernel<<<dim3(4, 1024), 512, 0, stream>>>(
        avh, avl, pwTh, pwTl, 1, nullptr, proj_b, out, 512, 4);
}

// Round 12
// 1195.138 us; speedup vs baseline: 1.1212x; 1.1212x over previous
//
#include <hip/hip_runtime.h>
#include <cstdint>
#include <cstddef>

// Problem constants (Swin window attention)
#define B_WIN   2048
#define N_TOK   64
#define C_DIM   512
#define H_HEADS 16
#define D_HEAD  32
#define K_DIM   512
#define M_ROWS  (B_WIN * 64)   // 131072

// Tiled operand layout for GEMM staging (bf16), 128-row granules:
//   T[mb][kt][s][r][e]  mb=row>>7, kt=k>>5, s=(k>>3)&3, r=row&127, e=k&7
//   flat elem = mb*65536 + kt*4096 + s*1024 + r*8 + e

typedef __bf16 bf16x8 __attribute__((ext_vector_type(8)));
typedef float  f32x4  __attribute__((ext_vector_type(4)));
typedef unsigned short u16x8 __attribute__((ext_vector_type(8)));

__device__ __forceinline__ unsigned short f2bf_rn(float f) {
    unsigned u = __float_as_uint(f);
    u += 0x7fffu + ((u >> 16) & 1u);
    return (unsigned short)(u >> 16);
}
__device__ __forceinline__ float bf2f(unsigned short h) {
    return __uint_as_float(((unsigned)h) << 16);
}
__device__ __forceinline__ void gload16(const void* g, void* l) {
    __builtin_amdgcn_global_load_lds(
        (const __attribute__((address_space(1))) void*)g,
        (__attribute__((address_space(3))) void*)l,
        16, 0, 0);
}

// ---------------------------------------------------------------------------
// bias_expand: bias_hn[h][i][j] = table[rel[i][j]][h]   (65536 floats)
// ---------------------------------------------------------------------------
__global__ void bias_expand_kernel(const float* __restrict__ bias_table,
                                   const int* __restrict__ rel_index,
                                   float* __restrict__ bias_hn) {
    int tid = blockIdx.x * 256 + threadIdx.x;
    int h  = tid >> 12;
    int ij = tid & 4095;
    bias_hn[tid] = bias_table[rel_index[ij] * H_HEADS + h];
}

// ---------------------------------------------------------------------------
// xsplit: x [M][512] fp32 -> Xh/Xl bf16 hi/lo in TILED layout.
// ---------------------------------------------------------------------------
__global__ __launch_bounds__(256) void xsplit_kernel(
    const float* __restrict__ x,
    unsigned short* __restrict__ Xh,
    unsigned short* __restrict__ Xl)
{
    size_t e8 = ((size_t)blockIdx.x * 256 + threadIdx.x) * 8;
    const int mb = (int)(e8 >> 16);
    const int w  = (int)(e8 & 65535);
    const int kt = w >> 12;
    const int s  = (w >> 10) & 3;
    const int r  = (w >> 3) & 127;
    const int m  = mb * 128 + r;
    const int k  = kt * 32 + s * 8;
    const float* src = &x[(size_t)m * 512 + k];
    float4 f0 = *reinterpret_cast<const float4*>(src);
    float4 f1 = *reinterpret_cast<const float4*>(src + 4);
    float fv[8] = {f0.x, f0.y, f0.z, f0.w, f1.x, f1.y, f1.z, f1.w};
    u16x8 hi, lo;
#pragma unroll
    for (int j = 0; j < 8; ++j) {
        unsigned short h = f2bf_rn(fv[j]);
        hi[j] = h;
        lo[j] = f2bf_rn(fv[j] - bf2f(h));
    }
    *reinterpret_cast<u16x8*>(&Xh[e8]) = hi;
    *reinterpret_cast<u16x8*>(&Xl[e8]) = lo;
}

// ---------------------------------------------------------------------------
// wsplit: w[512 k][Ncols n] -> wTh/wTl (rows=n, 512 k) in TILED layout
// ---------------------------------------------------------------------------
__global__ __launch_bounds__(256) void wsplit_kernel(
    const float* __restrict__ w,
    unsigned short* __restrict__ wTh,
    unsigned short* __restrict__ wTl,
    int Ncols)
{
    size_t e8 = ((size_t)blockIdx.x * 256 + threadIdx.x) * 8;
    const int mb = (int)(e8 >> 16);
    const int ww = (int)(e8 & 65535);
    const int kt = ww >> 12;
    const int s  = (ww >> 10) & 3;
    const int r  = (ww >> 3) & 127;
    const int n  = mb * 128 + r;
    const int k  = kt * 32 + s * 8;
    u16x8 hi, lo;
#pragma unroll
    for (int j = 0; j < 8; ++j) {
        float v = w[(size_t)(k + j) * Ncols + n];
        unsigned short h = f2bf_rn(v);
        hi[j] = h;
        lo[j] = f2bf_rn(v - bf2f(h));
    }
    *reinterpret_cast<u16x8*>(&wTh[e8]) = hi;
    *reinterpret_cast<u16x8*>(&wTl[e8]) = lo;
}

// ---------------------------------------------------------------------------
// bf16x3-split MFMA GEMM, 256x256 tile, BK=32, 16 steps, 8 waves (512 thr).
// R7's proven 2-buffer skeleton (stage -> frags -> MFMA -> vmcnt(0) ->
// barrier) scaled so one K-step = 96 MFMA/wave (~3700 cyc/SIMD) while the
// next stage is in flight -> the end-of-step drain waits on ~nothing.
// LDS: 2 x {Ah,Al,Bh,Bl}[256][32] = 128 KiB (dynamic), 1 block/CU.
// Wave-tile 128x64 (2m x 4n waves), acc[8][4] f32x4.
// ---------------------------------------------------------------------------
__global__ __launch_bounds__(512, 2) void gemm_mfma_kernel(
    const unsigned short* __restrict__ ATh,
    const unsigned short* __restrict__ ATl,
    const unsigned short* __restrict__ BTh,
    const unsigned short* __restrict__ BTl,
    int mode,
    float* __restrict__ qkv_out,
    const float* __restrict__ bias,
    float* __restrict__ out,
    int Ncols_out,
    int nb_grid)                 // blocks along n (Ncols/256)
{
    extern __shared__ __align__(16) unsigned short L[];  // 65536 elems
    // per-buffer base: buf*32768; variants: Ah +0, Al +8192, Bh +16384, Bl +24576

    const int t    = threadIdx.x;
    const int lane = t & 63;
    const int wave = t >> 6;             // 0..7
    const int lg   = lane >> 4;          // k-octet 0..3
    const int lr   = lane & 15;          // row within fragment
    const int wrow = (wave >> 2) * 128;  // 0,128
    const int wcol = (wave & 3) * 64;    // 0,64,128,192

    const int lin = blockIdx.x + gridDim.x * blockIdx.y;
    const int nwg = gridDim.x * gridDim.y;
    const int cpx = nwg >> 3;
    const int swz = (lin & 7) * cpx + (lin >> 3);
    const int m0  = (swz / nb_grid) * 256;
    const int n0  = (swz % nb_grid) * 256;
    const int mb0 = m0 >> 7;             // first 128-row granule
    const int nb0 = n0 >> 7;

    f32x4 acc[8][4];
#pragma unroll
    for (int i = 0; i < 8; ++i)
#pragma unroll
        for (int j = 0; j < 4; ++j) acc[i][j] = (f32x4){0.f, 0.f, 0.f, 0.f};

    // stage one K-step (64 KiB): 1024 chunks/variant, 2 per thread, 8 gloads
    auto stage = [&](int kt, int bi) {
        const int bufbase = bi * 32768;
#pragma unroll
        for (int i = 0; i < 2; ++i) {
            const int c = i * 512 + t;        // 0..1023
            const int r = c & 255;            // row in 256-tile
            const int s = c >> 8;             // k-octet pair.. 0..3
            const size_t gA = (size_t)(mb0 + (r >> 7)) * 65536
                            + (size_t)kt * 4096 + s * 1024 + (r & 127) * 8;
            const size_t gB = (size_t)(nb0 + (r >> 7)) * 65536
                            + (size_t)kt * 4096 + s * 1024 + (r & 127) * 8;
            const int lo = bufbase + s * 2048 + r * 8;   // wave-uniform + lane*8
            gload16(&ATh[gA], &L[lo]);
            gload16(&ATl[gA], &L[lo + 8192]);
            gload16(&BTh[gB], &L[lo + 16384]);
            gload16(&BTl[gB], &L[lo + 24576]);
        }
    };

    stage(0, 0);
    asm volatile("s_waitcnt vmcnt(0)" ::: "memory");
    __builtin_amdgcn_sched_barrier(0);
    __builtin_amdgcn_s_barrier();
    __builtin_amdgcn_sched_barrier(0);

#pragma unroll 2
    for (int ks = 0; ks < 16; ++ks) {
        const int cur = ks & 1;
        if (ks + 1 < 16) stage(ks + 1, cur ^ 1);
        const int bb = cur * 32768;

        // B-fragments once per step (held live: 8 x bf16x8)
        bf16x8 bh[4], bl[4];
#pragma unroll
        for (int ni = 0; ni < 4; ++ni) {
            const int off = bb + lg * 2048 + (wcol + ni * 16 + lr) * 8;
            bh[ni] = *reinterpret_cast<const bf16x8*>(&L[off + 16384]);
            bl[ni] = *reinterpret_cast<const bf16x8*>(&L[off + 24576]);
        }
        __builtin_amdgcn_s_setprio(1);
#pragma unroll
        for (int mi = 0; mi < 8; ++mi) {
            const int aoff = bb + lg * 2048 + (wrow + mi * 16 + lr) * 8;
            bf16x8 ah = *reinterpret_cast<const bf16x8*>(&L[aoff]);
            bf16x8 al = *reinterpret_cast<const bf16x8*>(&L[aoff + 8192]);
#pragma unroll
            for (int ni = 0; ni < 4; ++ni) {
                acc[mi][ni] = __builtin_amdgcn_mfma_f32_16x16x32_bf16(ah, bh[ni], acc[mi][ni], 0, 0, 0);
                acc[mi][ni] = __builtin_amdgcn_mfma_f32_16x16x32_bf16(ah, bl[ni], acc[mi][ni], 0, 0, 0);
                acc[mi][ni] = __builtin_amdgcn_mfma_f32_16x16x32_bf16(al, bh[ni], acc[mi][ni], 0, 0, 0);
            }
        }
        __builtin_amdgcn_s_setprio(0);

        // stage(ks+1) was issued ~3700 cyc ago -> this drain is ~free
        asm volatile("s_waitcnt vmcnt(0)" ::: "memory");
        __builtin_amdgcn_sched_barrier(0);
        __builtin_amdgcn_s_barrier();
        __builtin_amdgcn_sched_barrier(0);
    }

    // C/D layout: col = lane&15, row = (lane>>4)*4 + reg   [m89-verified]
    if (mode == 0) {
#pragma unroll
        for (int mi = 0; mi < 8; ++mi)
#pragma unroll
            for (int ni = 0; ni < 4; ++ni) {
                const int col  = n0 + wcol + ni * 16 + lr;
                const int tsel = col >> 9;
                const int h    = (col >> 5) & 15;
                const int dd   = col & 31;
#pragma unroll
                for (int reg = 0; reg < 4; ++reg) {
                    const int row = m0 + wrow + mi * 16 + lg * 4 + reg;
                    const int b = row >> 6, n = row & 63;
                    qkv_out[((((size_t)tsel * B_WIN + b) * H_HEADS + h) * N_TOK + n) * D_HEAD + dd]
                        = acc[mi][ni][reg];
                }
            }
    } else {
#pragma unroll
        for (int mi = 0; mi < 8; ++mi)
#pragma unroll
            for (int ni = 0; ni < 4; ++ni) {
                const int col = n0 + wcol + ni * 16 + lr;
                const float pb = bias[col];
#pragma unroll
                for (int reg = 0; reg < 4; ++reg) {
                    const int row = m0 + wrow + mi * 16 + lg * 4 + reg;
                    out[(size_t)row * Ncols_out + col] = acc[mi][ni][reg] + pb;
                }
            }
    }
}

// ---------------------------------------------------------------------------
// MFMA window attention (unchanged from R6/R7 — proven)
// ---------------------------------------------------------------------------
__global__ __launch_bounds__(256, 4) void attn_kernel(
    const float* __restrict__ qkv,        // [3][B][H][N][D]
    const float* __restrict__ bias_hn,    // [H][64][64]
    float* __restrict__ attn_map,         // [B][H][64][64]
    unsigned short* __restrict__ avh,     // tiled bf16 hi
    unsigned short* __restrict__ avl)     // tiled bf16 lo
{
    __shared__ __align__(16) unsigned short SM[14848];
    constexpr int QH = 0, QL = 2560, KH = 5120, KL = 7680;   // [64][40]
    constexpr int PH = 0, PL = 4608;                         // [64][72]
    constexpr int VTH = 10240, VTL = 12544;                  // [32][72]

    const int bh   = blockIdx.x;
    const int b    = bh >> 4;
    const int h    = bh & 15;
    const int t    = threadIdx.x;
    const int lane = t & 63;
    const int wv   = t >> 6;
    const int lg   = lane >> 4;
    const int lr   = lane & 15;

    const size_t plane = (size_t)B_WIN * H_HEADS * N_TOK * D_HEAD;
    const size_t base  = (size_t)bh * (N_TOK * D_HEAD);
    const float* qg = qkv + base;
    const float* kg = qkv + plane + base;
    const float* vg = qkv + 2 * plane + base;

    {
        const int r  = t >> 2;
        const int c0 = (t & 3) * 8;
        float4 a0 = *reinterpret_cast<const float4*>(&qg[r * 32 + c0]);
        float4 a1 = *reinterpret_cast<const float4*>(&qg[r * 32 + c0 + 4]);
        float qv[8] = {a0.x, a0.y, a0.z, a0.w, a1.x, a1.y, a1.z, a1.w};
        u16x8 hi, lo;
#pragma unroll
        for (int j = 0; j < 8; ++j) {
            unsigned short hh = f2bf_rn(qv[j]);
            hi[j] = hh; lo[j] = f2bf_rn(qv[j] - bf2f(hh));
        }
        *reinterpret_cast<u16x8*>(&SM[QH + r * 40 + c0]) = hi;
        *reinterpret_cast<u16x8*>(&SM[QL + r * 40 + c0]) = lo;

        float4 k0 = *reinterpret_cast<const float4*>(&kg[r * 32 + c0]);
        float4 k1 = *reinterpret_cast<const float4*>(&kg[r * 32 + c0 + 4]);
        float kv[8] = {k0.x, k0.y, k0.z, k0.w, k1.x, k1.y, k1.z, k1.w};
#pragma unroll
        for (int j = 0; j < 8; ++j) {
            unsigned short hh = f2bf_rn(kv[j]);
            hi[j] = hh; lo[j] = f2bf_rn(kv[j] - bf2f(hh));
        }
        *reinterpret_cast<u16x8*>(&SM[KH + r * 40 + c0]) = hi;
        *reinterpret_cast<u16x8*>(&SM[KL + r * 40 + c0]) = lo;

        float4 v0 = *reinterpret_cast<const float4*>(&vg[r * 32 + c0]);
        float4 v1 = *reinterpret_cast<const float4*>(&vg[r * 32 + c0 + 4]);
        float vv[8] = {v0.x, v0.y, v0.z, v0.w, v1.x, v1.y, v1.z, v1.w};
#pragma unroll
        for (int u = 0; u < 8; ++u) {
            const int d = c0 + u;
            unsigned short hh = f2bf_rn(vv[u]);
            SM[VTH + d * 72 + r] = hh;
            SM[VTL + d * 72 + r] = f2bf_rn(vv[u] - bf2f(hh));
        }
    }
    __syncthreads();

    float bias[4][4];
#pragma unroll
    for (int reg = 0; reg < 4; ++reg)
#pragma unroll
        for (int c = 0; c < 4; ++c)
            bias[reg][c] = bias_hn[(h << 12) + ((wv * 16 + lg * 4 + reg) << 6) + c * 16 + lr];

    const int ar = wv * 16 + lr;
    bf16x8 qa_h = *reinterpret_cast<const bf16x8*>(&SM[QH + ar * 40 + lg * 8]);
    bf16x8 qa_l = *reinterpret_cast<const bf16x8*>(&SM[QL + ar * 40 + lg * 8]);
    f32x4 S[4];
#pragma unroll
    for (int c = 0; c < 4; ++c) {
        const int br = c * 16 + lr;
        bf16x8 kb_h = *reinterpret_cast<const bf16x8*>(&SM[KH + br * 40 + lg * 8]);
        bf16x8 kb_l = *reinterpret_cast<const bf16x8*>(&SM[KL + br * 40 + lg * 8]);
        f32x4 s = (f32x4){0.f, 0.f, 0.f, 0.f};
        s = __builtin_amdgcn_mfma_f32_16x16x32_bf16(qa_h, kb_h, s, 0, 0, 0);
        s = __builtin_amdgcn_mfma_f32_16x16x32_bf16(qa_h, kb_l, s, 0, 0, 0);
        s = __builtin_amdgcn_mfma_f32_16x16x32_bf16(qa_l, kb_h, s, 0, 0, 0);
        S[c] = s;
    }
    __syncthreads();   // Q/K region dead -> reusable for P

    const float scale = 0.1767766952966369f;  // 32^-0.5
    float p[4][4], mx[4], sm[4];
#pragma unroll
    for (int reg = 0; reg < 4; ++reg) mx[reg] = -1e30f;
#pragma unroll
    for (int reg = 0; reg < 4; ++reg)
#pragma unroll
        for (int c = 0; c < 4; ++c) {
            float s = fmaf(S[c][reg], scale, bias[reg][c]);
            p[reg][c] = s;
            mx[reg] = fmaxf(mx[reg], s);
        }
#pragma unroll
    for (int reg = 0; reg < 4; ++reg) {
        mx[reg] = fmaxf(mx[reg], __shfl_xor(mx[reg], 1));
        mx[reg] = fmaxf(mx[reg], __shfl_xor(mx[reg], 2));
        mx[reg] = fmaxf(mx[reg], __shfl_xor(mx[reg], 4));
        mx[reg] = fmaxf(mx[reg], __shfl_xor(mx[reg], 8));
        sm[reg] = 0.f;
    }
#pragma unroll
    for (int reg = 0; reg < 4; ++reg)
#pragma unroll
        for (int c = 0; c < 4; ++c) {
            float e = __expf(p[reg][c] - mx[reg]);
            p[reg][c] = e;
            sm[reg] += e;
        }
#pragma unroll
    for (int reg = 0; reg < 4; ++reg) {
        sm[reg] += __shfl_xor(sm[reg], 1);
        sm[reg] += __shfl_xor(sm[reg], 2);
        sm[reg] += __shfl_xor(sm[reg], 4);
        sm[reg] += __shfl_xor(sm[reg], 8);
        const float inv = 1.0f / sm[reg];
#pragma unroll
        for (int c = 0; c < 4; ++c) p[reg][c] *= inv;
    }

    const size_t amb = (size_t)bh * 4096;
#pragma unroll
    for (int reg = 0; reg < 4; ++reg) {
        const int R = wv * 16 + lg * 4 + reg;
#pragma unroll
        for (int c = 0; c < 4; ++c) {
            const int C = c * 16 + lr;
            const float own = p[reg][c];
            attn_map[amb + R * 64 + C] = own;
            const float mate = __shfl_xor(own, 1);
            if (!(lr & 1)) {
                unsigned short h0 = f2bf_rn(own);
                unsigned short l0 = f2bf_rn(own - bf2f(h0));
                unsigned short h1 = f2bf_rn(mate);
                unsigned short l1 = f2bf_rn(mate - bf2f(h1));
                *reinterpret_cast<unsigned*>(&SM[PH + R * 72 + C]) =
                    (unsigned)h0 | ((unsigned)h1 << 16);
                *reinterpret_cast<unsigned*>(&SM[PL + R * 72 + C]) =
                    (unsigned)l0 | ((unsigned)l1 << 16);
            }
        }
    }
    // no barrier: wave w's PV a-frags read rows 16wv..16wv+15 = its own writes

    f32x4 O[2];
    O[0] = (f32x4){0.f, 0.f, 0.f, 0.f};
    O[1] = (f32x4){0.f, 0.f, 0.f, 0.f};
#pragma unroll
    for (int kk = 0; kk < 2; ++kk) {
        const int pr = wv * 16 + lr;
        bf16x8 pa_h = *reinterpret_cast<const bf16x8*>(&SM[PH + pr * 72 + kk * 32 + lg * 8]);
        bf16x8 pa_l = *reinterpret_cast<const bf16x8*>(&SM[PL + pr * 72 + kk * 32 + lg * 8]);
#pragma unroll
        for (int n = 0; n < 2; ++n) {
            const int vr = n * 16 + lr;
            bf16x8 vb_h = *reinterpret_cast<const bf16x8*>(&SM[VTH + vr * 72 + kk * 32 + lg * 8]);
            bf16x8 vb_l = *reinterpret_cast<const bf16x8*>(&SM[VTL + vr * 72 + kk * 32 + lg * 8]);
            O[n] = __builtin_amdgcn_mfma_f32_16x16x32_bf16(pa_h, vb_h, O[n], 0, 0, 0);
            O[n] = __builtin_amdgcn_mfma_f32_16x16x32_bf16(pa_h, vb_l, O[n], 0, 0, 0);
            O[n] = __builtin_amdgcn_mfma_f32_16x16x32_bf16(pa_l, vb_h, O[n], 0, 0, 0);
        }
    }

    const int mb = b >> 1;
#pragma unroll
    for (int n = 0; n < 2; ++n)
#pragma unroll
        for (int reg = 0; reg < 4; ++reg) {
            const int R  = wv * 16 + lg * 4 + reg;
            const int d  = n * 16 + lr;
            const int rl = (b & 1) * 64 + R;
            const float o = O[n][reg];
            unsigned short oh = f2bf_rn(o);
            unsigned short ol = f2bf_rn(o - bf2f(oh));
            size_t off = (size_t)mb * 65536 + (size_t)h * 4096
                       + (size_t)(d >> 3) * 1024 + (size_t)rl * 8 + (d & 7);
            avh[off] = oh;
            avl[off] = ol;
        }
}

// ---------------------------------------------------------------------------
extern "C" void kernel_launch(void* const* d_in, const int* in_sizes, int n_in,
                              void* d_out, int out_size, void* d_ws, size_t ws_size,
                              hipStream_t stream) {
    const float* x          = (const float*)d_in[0];
    const float* qkv_w      = (const float*)d_in[1];
    const float* proj_w     = (const float*)d_in[2];
    const float* proj_b     = (const float*)d_in[3];
    const float* bias_table = (const float*)d_in[4];
    const int*   rel_index  = (const int*)d_in[5];

    float* out      = (float*)d_out;                           // [131072][512]
    float* attn_map = (float*)d_out + (size_t)M_ROWS * C_DIM;  // [B][H][64][64]

    // d_ws: Xh | Xl (tiled bf16) | qkv fp32   (same as R7)
    // avh/avl alias Xh/Xl (dead after QKV GEMM).
    unsigned short* Xh  = (unsigned short*)d_ws;
    unsigned short* Xl  = Xh + (size_t)M_ROWS * 512;
    float*          qkv = (float*)(Xl + (size_t)M_ROWS * 512);
    unsigned short* avh = Xh;
    unsigned short* avl = Xl;

    // parking: qkv_w split -> attn_map region of d_out (dead until attn
    // overwrites it); proj_w split -> qkv head (dead after attn reads qkv);
    // bias_hn -> out head (out written only by the final proj GEMM).
    unsigned short* qwTh = (unsigned short*)attn_map;
    unsigned short* qwTl = qwTh + (size_t)1536 * 512;
    unsigned short* pwTh = (unsigned short*)qkv;
    unsigned short* pwTl = pwTh + (size_t)512 * 512;
    float* bias_hn = out;   // 65536 floats at head of out region

    bias_expand_kernel<<<256, 256, 0, stream>>>(bias_table, rel_index, bias_hn);
    xsplit_kernel<<<M_ROWS * 512 / 2048, 256, 0, stream>>>(x, Xh, Xl);
    wsplit_kernel<<<384, 256, 0, stream>>>(qkv_w, qwTh, qwTl, 1536);
    gemm_mfma_kernel<<<dim3(6, 512), 512, 131072, stream>>>(
        Xh, Xl, qwTh, qwTl, 0, qkv, nullptr, nullptr, 1536, 6);
    attn_kernel<<<B_WIN * H_HEADS, 256, 0, stream>>>(
        qkv, bias_hn, attn_map, avh, avl);
    wsplit_kernel<<<128, 256, 0, stream>>>(proj_w, pwTh, pwTl, 512);
    gemm_mfma_kernel<<<dim3(2, 512), 512, 131072, stream>>>(
        avh, avl, pwTh, pwTl, 1, nullptr, proj_b, out, 512, 2);
}

// Round 13
// 1179.327 us; speedup vs baseline: 1.1362x; 1.0134x over previous
//
#include <hip/hip_runtime.h>
#include <cstdint>
#include <cstddef>

// Problem constants (Swin window attention)
#define B_WIN   2048
#define N_TOK   64
#define C_DIM   512
#define H_HEADS 16
#define D_HEAD  32
#define K_DIM   512
#define M_ROWS  (B_WIN * 64)   // 131072

// Tiled operand layout for GEMM staging (bf16), 128-row granules:
//   T[mb][kt][s][r][e]  mb=row>>7, kt=k>>5, s=(k>>3)&3, r=row&127, e=k&7
//   flat elem = mb*65536 + kt*4096 + s*1024 + r*8 + e

typedef __bf16 bf16x8 __attribute__((ext_vector_type(8)));
typedef float  f32x4  __attribute__((ext_vector_type(4)));
typedef unsigned short u16x8 __attribute__((ext_vector_type(8)));

__device__ __forceinline__ unsigned short f2bf_rn(float f) {
    unsigned u = __float_as_uint(f);
    u += 0x7fffu + ((u >> 16) & 1u);
    return (unsigned short)(u >> 16);
}
__device__ __forceinline__ float bf2f(unsigned short h) {
    return __uint_as_float(((unsigned)h) << 16);
}
__device__ __forceinline__ void gload16(const void* g, void* l) {
    __builtin_amdgcn_global_load_lds(
        (const __attribute__((address_space(1))) void*)g,
        (__attribute__((address_space(3))) void*)l,
        16, 0, 0);
}

// ---------------------------------------------------------------------------
// prep: fused {xsplit | qkv wsplit | bias_expand} (grid-partitioned).
//   blocks [0, 32768)        : xsplit  x -> Xh/Xl (tiled)
//   blocks [32768, 33152)    : wsplit  qkv_w -> qwTh/qwTl (tiled, Ncols=1536)
//   blocks [33152, 33408)    : bias_hn[h][i][j] = table[rel[i][j]][h]
// ---------------------------------------------------------------------------
__global__ __launch_bounds__(256) void prep_kernel(
    const float* __restrict__ x,
    unsigned short* __restrict__ Xh,
    unsigned short* __restrict__ Xl,
    const float* __restrict__ qkv_w,
    unsigned short* __restrict__ qwTh,
    unsigned short* __restrict__ qwTl,
    const float* __restrict__ bias_table,
    const int* __restrict__ rel_index,
    float* __restrict__ bias_hn)
{
    const int blk = blockIdx.x;
    if (blk < 32768) {
        // ---- xsplit ----
        size_t e8 = ((size_t)blk * 256 + threadIdx.x) * 8;
        const int mb = (int)(e8 >> 16);
        const int w  = (int)(e8 & 65535);
        const int kt = w >> 12;
        const int s  = (w >> 10) & 3;
        const int r  = (w >> 3) & 127;
        const int m  = mb * 128 + r;
        const int k  = kt * 32 + s * 8;
        const float* src = &x[(size_t)m * 512 + k];
        float4 f0 = *reinterpret_cast<const float4*>(src);
        float4 f1 = *reinterpret_cast<const float4*>(src + 4);
        float fv[8] = {f0.x, f0.y, f0.z, f0.w, f1.x, f1.y, f1.z, f1.w};
        u16x8 hi, lo;
#pragma unroll
        for (int j = 0; j < 8; ++j) {
            unsigned short h = f2bf_rn(fv[j]);
            hi[j] = h;
            lo[j] = f2bf_rn(fv[j] - bf2f(h));
        }
        *reinterpret_cast<u16x8*>(&Xh[e8]) = hi;
        *reinterpret_cast<u16x8*>(&Xl[e8]) = lo;
    } else if (blk < 33152) {
        // ---- wsplit qkv_w (Ncols = 1536) ----
        size_t e8 = ((size_t)(blk - 32768) * 256 + threadIdx.x) * 8;
        const int mb = (int)(e8 >> 16);
        const int ww = (int)(e8 & 65535);
        const int kt = ww >> 12;
        const int s  = (ww >> 10) & 3;
        const int r  = (ww >> 3) & 127;
        const int n  = mb * 128 + r;
        const int k  = kt * 32 + s * 8;
        u16x8 hi, lo;
#pragma unroll
        for (int j = 0; j < 8; ++j) {
            float v = qkv_w[(size_t)(k + j) * 1536 + n];
            unsigned short h = f2bf_rn(v);
            hi[j] = h;
            lo[j] = f2bf_rn(v - bf2f(h));
        }
        *reinterpret_cast<u16x8*>(&qwTh[e8]) = hi;
        *reinterpret_cast<u16x8*>(&qwTl[e8]) = lo;
    } else {
        // ---- bias expand ----
        int tid = (blk - 33152) * 256 + threadIdx.x;
        int h  = tid >> 12;
        int ij = tid & 4095;
        bias_hn[tid] = bias_table[rel_index[ij] * H_HEADS + h];
    }
}

// ---------------------------------------------------------------------------
// wsplit (proj_w only; must run after attn because of its parking region)
// ---------------------------------------------------------------------------
__global__ __launch_bounds__(256) void wsplit_kernel(
    const float* __restrict__ w,
    unsigned short* __restrict__ wTh,
    unsigned short* __restrict__ wTl,
    int Ncols)
{
    size_t e8 = ((size_t)blockIdx.x * 256 + threadIdx.x) * 8;
    const int mb = (int)(e8 >> 16);
    const int ww = (int)(e8 & 65535);
    const int kt = ww >> 12;
    const int s  = (ww >> 10) & 3;
    const int r  = (ww >> 3) & 127;
    const int n  = mb * 128 + r;
    const int k  = kt * 32 + s * 8;
    u16x8 hi, lo;
#pragma unroll
    for (int j = 0; j < 8; ++j) {
        float v = w[(size_t)(k + j) * Ncols + n];
        unsigned short h = f2bf_rn(v);
        hi[j] = h;
        lo[j] = f2bf_rn(v - bf2f(h));
    }
    *reinterpret_cast<u16x8*>(&wTh[e8]) = hi;
    *reinterpret_cast<u16x8*>(&wTl[e8]) = lo;
}

// ---------------------------------------------------------------------------
// bf16x3-split MFMA GEMM, 256x256 tile, BK=32, 16 steps, 8 waves (512 thr).
// R12-proven skeleton. R13 change: inner MFMA order is pass-major within mi
// (hh ni0-3, hl ni0-3, lh ni0-3) -> dependent MFMAs to the same acc are 4
// apart (~78 cyc) instead of back-to-back. Per-acc accumulation order is
// unchanged (hh->hl->lh): bit-identical results.
// LDS: 2 x {Ah,Al,Bh,Bl}[256][32] = 128 KiB (dynamic), 1 block/CU.
// ---------------------------------------------------------------------------
__global__ __launch_bounds__(512, 2) void gemm_mfma_kernel(
    const unsigned short* __restrict__ ATh,
    const unsigned short* __restrict__ ATl,
    const unsigned short* __restrict__ BTh,
    const unsigned short* __restrict__ BTl,
    int mode,
    float* __restrict__ qkv_out,
    const float* __restrict__ bias,
    float* __restrict__ out,
    int Ncols_out,
    int nb_grid)                 // blocks along n (Ncols/256)
{
    extern __shared__ __align__(16) unsigned short L[];  // 65536 elems
    // per-buffer base: buf*32768; variants: Ah +0, Al +8192, Bh +16384, Bl +24576

    const int t    = threadIdx.x;
    const int lane = t & 63;
    const int wave = t >> 6;             // 0..7
    const int lg   = lane >> 4;          // k-octet 0..3
    const int lr   = lane & 15;          // row within fragment
    const int wrow = (wave >> 2) * 128;  // 0,128
    const int wcol = (wave & 3) * 64;    // 0,64,128,192

    const int lin = blockIdx.x + gridDim.x * blockIdx.y;
    const int nwg = gridDim.x * gridDim.y;
    const int cpx = nwg >> 3;
    const int swz = (lin & 7) * cpx + (lin >> 3);
    const int m0  = (swz / nb_grid) * 256;
    const int n0  = (swz % nb_grid) * 256;
    const int mb0 = m0 >> 7;             // first 128-row granule
    const int nb0 = n0 >> 7;

    f32x4 acc[8][4];
#pragma unroll
    for (int i = 0; i < 8; ++i)
#pragma unroll
        for (int j = 0; j < 4; ++j) acc[i][j] = (f32x4){0.f, 0.f, 0.f, 0.f};

    // stage one K-step (64 KiB): 1024 chunks/variant, 2 per thread, 8 gloads
    auto stage = [&](int kt, int bi) {
        const int bufbase = bi * 32768;
#pragma unroll
        for (int i = 0; i < 2; ++i) {
            const int c = i * 512 + t;        // 0..1023
            const int r = c & 255;            // row in 256-tile
            const int s = c >> 8;             // k-octet pair 0..3
            const size_t gA = (size_t)(mb0 + (r >> 7)) * 65536
                            + (size_t)kt * 4096 + s * 1024 + (r & 127) * 8;
            const size_t gB = (size_t)(nb0 + (r >> 7)) * 65536
                            + (size_t)kt * 4096 + s * 1024 + (r & 127) * 8;
            const int lo = bufbase + s * 2048 + r * 8;   // wave-uniform + lane*8
            gload16(&ATh[gA], &L[lo]);
            gload16(&ATl[gA], &L[lo + 8192]);
            gload16(&BTh[gB], &L[lo + 16384]);
            gload16(&BTl[gB], &L[lo + 24576]);
        }
    };

    stage(0, 0);
    asm volatile("s_waitcnt vmcnt(0)" ::: "memory");
    __builtin_amdgcn_sched_barrier(0);
    __builtin_amdgcn_s_barrier();
    __builtin_amdgcn_sched_barrier(0);

#pragma unroll 2
    for (int ks = 0; ks < 16; ++ks) {
        const int cur = ks & 1;
        if (ks + 1 < 16) stage(ks + 1, cur ^ 1);
        const int bb = cur * 32768;

        // B-fragments once per step (held live: 8 x bf16x8)
        bf16x8 bh[4], bl[4];
#pragma unroll
        for (int ni = 0; ni < 4; ++ni) {
            const int off = bb + lg * 2048 + (wcol + ni * 16 + lr) * 8;
            bh[ni] = *reinterpret_cast<const bf16x8*>(&L[off + 16384]);
            bl[ni] = *reinterpret_cast<const bf16x8*>(&L[off + 24576]);
        }
        __builtin_amdgcn_s_setprio(1);
#pragma unroll
        for (int mi = 0; mi < 8; ++mi) {
            const int aoff = bb + lg * 2048 + (wrow + mi * 16 + lr) * 8;
            bf16x8 ah = *reinterpret_cast<const bf16x8*>(&L[aoff]);
            bf16x8 al = *reinterpret_cast<const bf16x8*>(&L[aoff + 8192]);
            // pass-major: dependent writes to acc[mi][ni] are 4 MFMAs apart
#pragma unroll
            for (int ni = 0; ni < 4; ++ni)
                acc[mi][ni] = __builtin_amdgcn_mfma_f32_16x16x32_bf16(ah, bh[ni], acc[mi][ni], 0, 0, 0);
#pragma unroll
            for (int ni = 0; ni < 4; ++ni)
                acc[mi][ni] = __builtin_amdgcn_mfma_f32_16x16x32_bf16(ah, bl[ni], acc[mi][ni], 0, 0, 0);
#pragma unroll
            for (int ni = 0; ni < 4; ++ni)
                acc[mi][ni] = __builtin_amdgcn_mfma_f32_16x16x32_bf16(al, bh[ni], acc[mi][ni], 0, 0, 0);
        }
        __builtin_amdgcn_s_setprio(0);

        // stage(ks+1) was issued ~3700 cyc ago -> this drain is ~free
        asm volatile("s_waitcnt vmcnt(0)" ::: "memory");
        __builtin_amdgcn_sched_barrier(0);
        __builtin_amdgcn_s_barrier();
        __builtin_amdgcn_sched_barrier(0);
    }

    // C/D layout: col = lane&15, row = (lane>>4)*4 + reg   [m89-verified]
    if (mode == 0) {
#pragma unroll
        for (int mi = 0; mi < 8; ++mi)
#pragma unroll
            for (int ni = 0; ni < 4; ++ni) {
                const int col  = n0 + wcol + ni * 16 + lr;
                const int tsel = col >> 9;
                const int h    = (col >> 5) & 15;
                const int dd   = col & 31;
#pragma unroll
                for (int reg = 0; reg < 4; ++reg) {
                    const int row = m0 + wrow + mi * 16 + lg * 4 + reg;
                    const int b = row >> 6, n = row & 63;
                    qkv_out[((((size_t)tsel * B_WIN + b) * H_HEADS + h) * N_TOK + n) * D_HEAD + dd]
                        = acc[mi][ni][reg];
                }
            }
    } else {
#pragma unroll
        for (int mi = 0; mi < 8; ++mi)
#pragma unroll
            for (int ni = 0; ni < 4; ++ni) {
                const int col = n0 + wcol + ni * 16 + lr;
                const float pb = bias[col];
#pragma unroll
                for (int reg = 0; reg < 4; ++reg) {
                    const int row = m0 + wrow + mi * 16 + lg * 4 + reg;
                    out[(size_t)row * Ncols_out + col] = acc[mi][ni][reg] + pb;
                }
            }
    }
}

// ---------------------------------------------------------------------------
// MFMA window attention (unchanged from R6/R7 — proven)
// ---------------------------------------------------------------------------
__global__ __launch_bounds__(256, 4) void attn_kernel(
    const float* __restrict__ qkv,        // [3][B][H][N][D]
    const float* __restrict__ bias_hn,    // [H][64][64]
    float* __restrict__ attn_map,         // [B][H][64][64]
    unsigned short* __restrict__ avh,     // tiled bf16 hi
    unsigned short* __restrict__ avl)     // tiled bf16 lo
{
    __shared__ __align__(16) unsigned short SM[14848];
    constexpr int QH = 0, QL = 2560, KH = 5120, KL = 7680;   // [64][40]
    constexpr int PH = 0, PL = 4608;                         // [64][72]
    constexpr int VTH = 10240, VTL = 12544;                  // [32][72]

    const int bh   = blockIdx.x;
    const int b    = bh >> 4;
    const int h    = bh & 15;
    const int t    = threadIdx.x;
    const int lane = t & 63;
    const int wv   = t >> 6;
    const int lg   = lane >> 4;
    const int lr   = lane & 15;

    const size_t plane = (size_t)B_WIN * H_HEADS * N_TOK * D_HEAD;
    const size_t base  = (size_t)bh * (N_TOK * D_HEAD);
    const float* qg = qkv + base;
    const float* kg = qkv + plane + base;
    const float* vg = qkv + 2 * plane + base;

    {
        const int r  = t >> 2;
        const int c0 = (t & 3) * 8;
        float4 a0 = *reinterpret_cast<const float4*>(&qg[r * 32 + c0]);
        float4 a1 = *reinterpret_cast<const float4*>(&qg[r * 32 + c0 + 4]);
        float qv[8] = {a0.x, a0.y, a0.z, a0.w, a1.x, a1.y, a1.z, a1.w};
        u16x8 hi, lo;
#pragma unroll
        for (int j = 0; j < 8; ++j) {
            unsigned short hh = f2bf_rn(qv[j]);
            hi[j] = hh; lo[j] = f2bf_rn(qv[j] - bf2f(hh));
        }
        *reinterpret_cast<u16x8*>(&SM[QH + r * 40 + c0]) = hi;
        *reinterpret_cast<u16x8*>(&SM[QL + r * 40 + c0]) = lo;

        float4 k0 = *reinterpret_cast<const float4*>(&kg[r * 32 + c0]);
        float4 k1 = *reinterpret_cast<const float4*>(&kg[r * 32 + c0 + 4]);
        float kv[8] = {k0.x, k0.y, k0.z, k0.w, k1.x, k1.y, k1.z, k1.w};
#pragma unroll
        for (int j = 0; j < 8; ++j) {
            unsigned short hh = f2bf_rn(kv[j]);
            hi[j] = hh; lo[j] = f2bf_rn(kv[j] - bf2f(hh));
        }
        *reinterpret_cast<u16x8*>(&SM[KH + r * 40 + c0]) = hi;
        *reinterpret_cast<u16x8*>(&SM[KL + r * 40 + c0]) = lo;

        float4 v0 = *reinterpret_cast<const float4*>(&vg[r * 32 + c0]);
        float4 v1 = *reinterpret_cast<const float4*>(&vg[r * 32 + c0 + 4]);
        float vv[8] = {v0.x, v0.y, v0.z, v0.w, v1.x, v1.y, v1.z, v1.w};
#pragma unroll
        for (int u = 0; u < 8; ++u) {
            const int d = c0 + u;
            unsigned short hh = f2bf_rn(vv[u]);
            SM[VTH + d * 72 + r] = hh;
            SM[VTL + d * 72 + r] = f2bf_rn(vv[u] - bf2f(hh));
        }
    }
    __syncthreads();

    float bias[4][4];
#pragma unroll
    for (int reg = 0; reg < 4; ++reg)
#pragma unroll
        for (int c = 0; c < 4; ++c)
            bias[reg][c] = bias_hn[(h << 12) + ((wv * 16 + lg * 4 + reg) << 6) + c * 16 + lr];

    const int ar = wv * 16 + lr;
    bf16x8 qa_h = *reinterpret_cast<const bf16x8*>(&SM[QH + ar * 40 + lg * 8]);
    bf16x8 qa_l = *reinterpret_cast<const bf16x8*>(&SM[QL + ar * 40 + lg * 8]);
    f32x4 S[4];
#pragma unroll
    for (int c = 0; c < 4; ++c) {
        const int br = c * 16 + lr;
        bf16x8 kb_h = *reinterpret_cast<const bf16x8*>(&SM[KH + br * 40 + lg * 8]);
        bf16x8 kb_l = *reinterpret_cast<const bf16x8*>(&SM[KL + br * 40 + lg * 8]);
        f32x4 s = (f32x4){0.f, 0.f, 0.f, 0.f};
        s = __builtin_amdgcn_mfma_f32_16x16x32_bf16(qa_h, kb_h, s, 0, 0, 0);
        s = __builtin_amdgcn_mfma_f32_16x16x32_bf16(qa_h, kb_l, s, 0, 0, 0);
        s = __builtin_amdgcn_mfma_f32_16x16x32_bf16(qa_l, kb_h, s, 0, 0, 0);
        S[c] = s;
    }
    __syncthreads();   // Q/K region dead -> reusable for P

    const float scale = 0.1767766952966369f;  // 32^-0.5
    float p[4][4], mx[4], sm[4];
#pragma unroll
    for (int reg = 0; reg < 4; ++reg) mx[reg] = -1e30f;
#pragma unroll
    for (int reg = 0; reg < 4; ++reg)
#pragma unroll
        for (int c = 0; c < 4; ++c) {
            float s = fmaf(S[c][reg], scale, bias[reg][c]);
            p[reg][c] = s;
            mx[reg] = fmaxf(mx[reg], s);
        }
#pragma unroll
    for (int reg = 0; reg < 4; ++reg) {
        mx[reg] = fmaxf(mx[reg], __shfl_xor(mx[reg], 1));
        mx[reg] = fmaxf(mx[reg], __shfl_xor(mx[reg], 2));
        mx[reg] = fmaxf(mx[reg], __shfl_xor(mx[reg], 4));
        mx[reg] = fmaxf(mx[reg], __shfl_xor(mx[reg], 8));
        sm[reg] = 0.f;
    }
#pragma unroll
    for (int reg = 0; reg < 4; ++reg)
#pragma unroll
        for (int c = 0; c < 4; ++c) {
            float e = __expf(p[reg][c] - mx[reg]);
            p[reg][c] = e;
            sm[reg] += e;
        }
#pragma unroll
    for (int reg = 0; reg < 4; ++reg) {
        sm[reg] += __shfl_xor(sm[reg], 1);
        sm[reg] += __shfl_xor(sm[reg], 2);
        sm[reg] += __shfl_xor(sm[reg], 4);
        sm[reg] += __shfl_xor(sm[reg], 8);
        const float inv = 1.0f / sm[reg];
#pragma unroll
        for (int c = 0; c < 4; ++c) p[reg][c] *= inv;
    }

    const size_t amb = (size_t)bh * 4096;
#pragma unroll
    for (int reg = 0; reg < 4; ++reg) {
        const int R = wv * 16 + lg * 4 + reg;
#pragma unroll
        for (int c = 0; c < 4; ++c) {
            const int C = c * 16 + lr;
            const float own = p[reg][c];
            attn_map[amb + R * 64 + C] = own;
            const float mate = __shfl_xor(own, 1);
            if (!(lr & 1)) {
                unsigned short h0 = f2bf_rn(own);
                unsigned short l0 = f2bf_rn(own - bf2f(h0));
                unsigned short h1 = f2bf_rn(mate);
                unsigned short l1 = f2bf_rn(mate - bf2f(h1));
                *reinterpret_cast<unsigned*>(&SM[PH + R * 72 + C]) =
                    (unsigned)h0 | ((unsigned)h1 << 16);
                *reinterpret_cast<unsigned*>(&SM[PL + R * 72 + C]) =
                    (unsigned)l0 | ((unsigned)l1 << 16);
            }
        }
    }
    // no barrier: wave w's PV a-frags read rows 16wv..16wv+15 = its own writes

    f32x4 O[2];
    O[0] = (f32x4){0.f, 0.f, 0.f, 0.f};
    O[1] = (f32x4){0.f, 0.f, 0.f, 0.f};
#pragma unroll
    for (int kk = 0; kk < 2; ++kk) {
        const int pr = wv * 16 + lr;
        bf16x8 pa_h = *reinterpret_cast<const bf16x8*>(&SM[PH + pr * 72 + kk * 32 + lg * 8]);
        bf16x8 pa_l = *reinterpret_cast<const bf16x8*>(&SM[PL + pr * 72 + kk * 32 + lg * 8]);
#pragma unroll
        for (int n = 0; n < 2; ++n) {
            const int vr = n * 16 + lr;
            bf16x8 vb_h = *reinterpret_cast<const bf16x8*>(&SM[VTH + vr * 72 + kk * 32 + lg * 8]);
            bf16x8 vb_l = *reinterpret_cast<const bf16x8*>(&SM[VTL + vr * 72 + kk * 32 + lg * 8]);
            O[n] = __builtin_amdgcn_mfma_f32_16x16x32_bf16(pa_h, vb_h, O[n], 0, 0, 0);
            O[n] = __builtin_amdgcn_mfma_f32_16x16x32_bf16(pa_h, vb_l, O[n], 0, 0, 0);
            O[n] = __builtin_amdgcn_mfma_f32_16x16x32_bf16(pa_l, vb_h, O[n], 0, 0, 0);
        }
    }

    const int mb = b >> 1;
#pragma unroll
    for (int n = 0; n < 2; ++n)
#pragma unroll
        for (int reg = 0; reg < 4; ++reg) {
            const int R  = wv * 16 + lg * 4 + reg;
            const int d  = n * 16 + lr;
            const int rl = (b & 1) * 64 + R;
            const float o = O[n][reg];
            unsigned short oh = f2bf_rn(o);
            unsigned short ol = f2bf_rn(o - bf2f(oh));
            size_t off = (size_t)mb * 65536 + (size_t)h * 4096
                       + (size_t)(d >> 3) * 1024 + (size_t)rl * 8 + (d & 7);
            avh[off] = oh;
            avl[off] = ol;
        }
}

// ---------------------------------------------------------------------------
extern "C" void kernel_launch(void* const* d_in, const int* in_sizes, int n_in,
                              void* d_out, int out_size, void* d_ws, size_t ws_size,
                              hipStream_t stream) {
    const float* x          = (const float*)d_in[0];
    const float* qkv_w      = (const float*)d_in[1];
    const float* proj_w     = (const float*)d_in[2];
    const float* proj_b     = (const float*)d_in[3];
    const float* bias_table = (const float*)d_in[4];
    const int*   rel_index  = (const int*)d_in[5];

    float* out      = (float*)d_out;                           // [131072][512]
    float* attn_map = (float*)d_out + (size_t)M_ROWS * C_DIM;  // [B][H][64][64]

    // d_ws: Xh | Xl (tiled bf16) | qkv fp32
    // avh/avl alias Xh/Xl (dead after QKV GEMM).
    unsigned short* Xh  = (unsigned short*)d_ws;
    unsigned short* Xl  = Xh + (size_t)M_ROWS * 512;
    float*          qkv = (float*)(Xl + (size_t)M_ROWS * 512);
    unsigned short* avh = Xh;
    unsigned short* avl = Xl;

    // parking: qkv_w split -> attn_map region of d_out (dead until attn
    // overwrites it); proj_w split -> qkv head (dead after attn reads qkv);
    // bias_hn -> out head (out written only by the final proj GEMM).
    unsigned short* qwTh = (unsigned short*)attn_map;
    unsigned short* qwTl = qwTh + (size_t)1536 * 512;
    unsigned short* pwTh = (unsigned short*)qkv;
    unsigned short* pwTl = pwTh + (size_t)512 * 512;
    float* bias_hn = out;   // 65536 floats at head of out region

    prep_kernel<<<33408, 256, 0, stream>>>(
        x, Xh, Xl, qkv_w, qwTh, qwTl, bias_table, rel_index, bias_hn);
    gemm_mfma_kernel<<<dim3(6, 512), 512, 131072, stream>>>(
        Xh, Xl, qwTh, qwTl, 0, qkv, nullptr, nullptr, 1536, 6);
    attn_kernel<<<B_WIN * H_HEADS, 256, 0, stream>>>(
        qkv, bias_hn, attn_map, avh, avl);
    wsplit_kernel<<<128, 256, 0, stream>>>(proj_w, pwTh, pwTl, 512);
    gemm_mfma_kernel<<<dim3(2, 512), 512, 131072, stream>>>(
        avh, avl, pwTh, pwTl, 1, nullptr, proj_b, out, 512, 2);
}